// Round 6
// baseline (115.844 us; speedup 1.0000x reference)
//
#include <hip/hip_runtime.h>
#include <stdint.h>

typedef short s8v __attribute__((ext_vector_type(8)));   // 8 x bf16 (4 VGPRs)
typedef float f4v __attribute__((ext_vector_type(4)));   // MFMA accumulator / NT vec

#define EMB_DIM 256
#define HW      1024
#define NROWS   32768
#define NELEM   (NROWS * EMB_DIM)     // 8388608

// ws layout (bytes)
#define PK_OFF   0u          // 512 KB packed bf16 codebook (B-fragments)
#define CBN_OFF  524288u     // 4 KB ||e||^2
#define PSQ_OFF  528384u     // 2 KB per-block sum(x^2) [512]
#define PSM_OFF  530432u     // 2 KB per-block sum(min-dist) [512]
#define DONE_OFF 532480u     // 4 B completion counter

__device__ __forceinline__ unsigned f2bf(float f) {
    union { float f; unsigned u; } c; c.f = f;
    unsigned u = c.u;
    return (u + 0x7FFFu + ((u >> 16) & 1u)) >> 16;   // RNE
}

// ---------------------------------------------------------------------------
// prep_cb: 64 blocks pack the codebook into MFMA B-fragments + ||e||^2.
// Also zeroes the completion counter (stream-ordered before vq_fused).
// pk frag (T,s,lane l=G*16+ci, j) = cb[T*16+ci][32s+8G+j]   (verified layout)
// ---------------------------------------------------------------------------
__global__ __launch_bounds__(256) void prep_cb(const float* __restrict__ cb,
                                               unsigned short* __restrict__ pk,
                                               float* __restrict__ cbn,
                                               unsigned* __restrict__ done) {
    int T = blockIdx.x, t = threadIdx.x;
    if (T == 0 && t == 0) *done = 0u;
    {   // ||e||^2
        int code = t >> 4, seg = t & 15;
        const float* src = cb + (size_t)(T * 16 + code) * EMB_DIM + seg * 16;
        float s2 = 0.f;
        #pragma unroll
        for (int k = 0; k < 4; ++k) {
            float4 v = *(const float4*)(src + 4 * k);
            s2 += v.x * v.x + v.y * v.y + v.z * v.z + v.w * v.w;
        }
        #pragma unroll
        for (int m = 1; m < 16; m <<= 1) s2 += __shfl_xor(s2, m, 64);
        if (seg == 0) cbn[T * 16 + code] = s2;
    }
    #pragma unroll
    for (int it = 0; it < 2; ++it) {
        int idx = t + 256 * it;
        int s = idx >> 6, l = idx & 63, G = l >> 4, ci = l & 15;
        const float* q = cb + (size_t)(T * 16 + ci) * EMB_DIM + 32 * s + 8 * G;
        float4 v0 = *(const float4*)(q);
        float4 v1 = *(const float4*)(q + 4);
        unsigned o0 = f2bf(v0.x) | (f2bf(v0.y) << 16);
        unsigned o1 = f2bf(v0.z) | (f2bf(v0.w) << 16);
        unsigned o2 = f2bf(v1.x) | (f2bf(v1.y) << 16);
        unsigned o3 = f2bf(v1.z) | (f2bf(v1.w) << 16);
        *(uint4*)((char*)pk + (size_t)T * 8192 + (size_t)idx * 16) =
            make_uint4(o0, o1, o2, o3);
    }
}

// ---------------------------------------------------------------------------
// vq_fused: 512 blocks x 256 thr (2 blocks/CU). Block owns 64 rows.
// Phase 1: nontemporal copy x->out, sum(x^2), LDS transpose -> bf16 A-frags.
// Phase 2: wave w holds 4 row-tiles in registers, scans its code-quarter with
//          per-block start stagger and a register double-buffer on B-frags.
// Last block to finish performs the final fp64 reduction (no fin dispatch).
// ---------------------------------------------------------------------------
__global__ __launch_bounds__(256, 2) void vq_fused(const float* __restrict__ x,
                                                   float* __restrict__ out,
                                                   const unsigned short* __restrict__ pk,
                                                   const float* __restrict__ cbn,
                                                   float* __restrict__ psq,
                                                   float* __restrict__ psm,
                                                   unsigned* __restrict__ done) {
    __shared__ float smemf[64 * 69];     // fp32 chunk staging (pad 69)
    __shared__ uint4 frag[4 * 8 * 64];   // 32 KB bf16 A-fragments
    __shared__ float mloc[4][64];        // per-wave per-row mins
    __shared__ float red[4];             // per-wave sum(x^2)
    __shared__ bool  lastf;
    __shared__ double dred[4];

    int t = threadIdx.x;
    int blk = blockIdx.x;
    int b = blk >> 4, p0 = (blk & 15) << 6;   // 64 rows: [p0, p0+64) of batch b
    const float* xb = x   + (size_t)b * (EMB_DIM * HW) + p0;
    float*       ob = out + (size_t)b * (EMB_DIM * HW) + p0;

    int l = t & 63, w = t >> 6;
    int G = l >> 4, ci = l & 15;

    // ---- phase 1: copy + sq + transpose to A-frags (4 chunks of 64 dims) ----
    float sq = 0.f;
    int pq = t & 15, dd = t >> 4;
    for (int kd = 0; kd < 4; ++kd) {
        #pragma unroll
        for (int c2 = 0; c2 < 4; ++c2) {
            int dl = dd + 16 * c2;              // local dim in chunk
            size_t off = (size_t)(kd * 64 + dl) * HW + 4 * pq;
            f4v v = __builtin_nontemporal_load((const f4v*)(xb + off));
            __builtin_nontemporal_store(v, (f4v*)(ob + off));
            sq += v.x * v.x + v.y * v.y + v.z * v.z + v.w * v.w;
            float* dst = &smemf[dl * 69 + 4 * pq];
            dst[0] = v.x; dst[1] = v.y; dst[2] = v.z; dst[3] = v.w;
        }
        __syncthreads();
        #pragma unroll
        for (int it = 0; it < 2; ++it) {
            int f = t + 256 * it;
            int fl = f & 63, sL = (f >> 6) & 1, R = f >> 7;
            int fG = fl >> 4, fci = fl & 15;
            const float* q = &smemf[(32 * sL + 8 * fG) * 69 + 16 * R + fci];
            unsigned o0 = f2bf(q[0])   | (f2bf(q[69])  << 16);
            unsigned o1 = f2bf(q[138]) | (f2bf(q[207]) << 16);
            unsigned o2 = f2bf(q[276]) | (f2bf(q[345]) << 16);
            unsigned o3 = f2bf(q[414]) | (f2bf(q[483]) << 16);
            frag[(R * 8 + 2 * kd + sL) * 64 + fl] = make_uint4(o0, o1, o2, o3);
        }
        __syncthreads();
    }
    #pragma unroll
    for (int m = 1; m < 64; m <<= 1) sq += __shfl_xor(sq, m, 64);
    if (l == 0) red[w] = sq;

    // ---- phase 2: A-frags (all 4 row-tiles) into registers ----
    s8v a[4][8];
    #pragma unroll
    for (int R = 0; R < 4; ++R)
        #pragma unroll
        for (int s = 0; s < 8; ++s)
            a[R][s] = *(const s8v*)&frag[(R * 8 + s) * 64 + l];

    float mv[4][4];
    #pragma unroll
    for (int R = 0; R < 4; ++R)
        #pragma unroll
        for (int r = 0; r < 4; ++r) mv[R][r] = 1e30f;

    // wave w scans its quarter (tiles w*16..w*16+15), staggered start per
    // block, with a register double-buffer on the B-fragments.
    const char* lbase = (const char*)pk + (size_t)l * 16;
    int qbase = w * 16;
    int off = blk & 15;
    s8v cur[8], nxt[8];
    {
        const char* pt = lbase + (size_t)(qbase + off) * 8192;
        #pragma unroll
        for (int s = 0; s < 8; ++s) cur[s] = *(const s8v*)(pt + (size_t)s * 1024);
    }
    #pragma unroll 2
    for (int i = 0; i < 16; ++i) {
        int Tn = qbase + ((off + ((i + 1) & 15)) & 15);
        const char* pn = lbase + (size_t)Tn * 8192;
        #pragma unroll
        for (int s = 0; s < 8; ++s) nxt[s] = *(const s8v*)(pn + (size_t)s * 1024);

        f4v ac0 = {0.f,0.f,0.f,0.f}, ac1 = {0.f,0.f,0.f,0.f};
        f4v ac2 = {0.f,0.f,0.f,0.f}, ac3 = {0.f,0.f,0.f,0.f};
        #pragma unroll
        for (int s = 0; s < 8; ++s) {
            ac0 = __builtin_amdgcn_mfma_f32_16x16x32_bf16(a[0][s], cur[s], ac0, 0, 0, 0);
            ac1 = __builtin_amdgcn_mfma_f32_16x16x32_bf16(a[1][s], cur[s], ac1, 0, 0, 0);
            ac2 = __builtin_amdgcn_mfma_f32_16x16x32_bf16(a[2][s], cur[s], ac2, 0, 0, 0);
            ac3 = __builtin_amdgcn_mfma_f32_16x16x32_bf16(a[3][s], cur[s], ac3, 0, 0, 0);
        }
        int Tc = qbase + ((off + i) & 15);
        float cv = cbn[Tc * 16 + ci];
        #pragma unroll
        for (int r = 0; r < 4; ++r) {
            mv[0][r] = fminf(mv[0][r], cv - 2.f * ac0[r]);
            mv[1][r] = fminf(mv[1][r], cv - 2.f * ac1[r]);
            mv[2][r] = fminf(mv[2][r], cv - 2.f * ac2[r]);
            mv[3][r] = fminf(mv[3][r], cv - 2.f * ac3[r]);
        }
        #pragma unroll
        for (int s = 0; s < 8; ++s) cur[s] = nxt[s];
    }

    // ---- min over the 16 code-lanes; stash per-wave row mins in LDS ----
    #pragma unroll
    for (int R = 0; R < 4; ++R)
        #pragma unroll
        for (int r = 0; r < 4; ++r) {
            float v = mv[R][r];
            #pragma unroll
            for (int m = 1; m < 16; m <<= 1) v = fminf(v, __shfl_xor(v, m, 64));
            mv[R][r] = v;
        }
    if (ci == 0) {
        #pragma unroll
        for (int R = 0; R < 4; ++R)
            #pragma unroll
            for (int r = 0; r < 4; ++r)
                mloc[w][16 * R + 4 * G + r] = mv[R][r];
    }
    __syncthreads();

    // ---- combine: per-row min over 4 waves, sum rows, publish partials ----
    if (t < 64) {
        float m = fminf(fminf(mloc[0][t], mloc[1][t]),
                        fminf(mloc[2][t], mloc[3][t]));
        #pragma unroll
        for (int mm = 1; mm < 64; mm <<= 1) m += __shfl_xor(m, mm, 64);
        if (t == 0) {
            __hip_atomic_store(&psm[blk], m, __ATOMIC_RELAXED, __HIP_MEMORY_SCOPE_AGENT);
            __hip_atomic_store(&psq[blk], red[0] + red[1] + red[2] + red[3],
                               __ATOMIC_RELAXED, __HIP_MEMORY_SCOPE_AGENT);
            __threadfence();
            unsigned old = __hip_atomic_fetch_add(done, 1u, __ATOMIC_RELAXED,
                                                  __HIP_MEMORY_SCOPE_AGENT);
            lastf = (old == 511u);
        }
    }
    __syncthreads();

    // ---- last block: final deterministic fp64 reduction + scalar outputs ----
    if (lastf) {
        __threadfence();
        double s = 0.0;
        #pragma unroll
        for (int h = 0; h < 2; ++h) {
            int idx = t + 256 * h;
            s += (double)__hip_atomic_load(&psm[idx], __ATOMIC_RELAXED, __HIP_MEMORY_SCOPE_AGENT)
               + (double)__hip_atomic_load(&psq[idx], __ATOMIC_RELAXED, __HIP_MEMORY_SCOPE_AGENT);
        }
        #pragma unroll
        for (int m = 1; m < 64; m <<= 1) s += __shfl_xor(s, m, 64);
        if (l == 0) dred[w] = s;
        __syncthreads();
        if (t == 0) {
            double tot = dred[0] + dred[1] + dred[2] + dred[3];
            double cl = tot / (double)NELEM;
            out[NELEM + 0] = (float)(1.25 * cl);
            out[NELEM + 1] = (float)cl;
            out[NELEM + 2] = (float)cl;
        }
    }
}

extern "C" void kernel_launch(void* const* d_in, const int* in_sizes, int n_in,
                              void* d_out, int out_size, void* d_ws, size_t ws_size,
                              hipStream_t stream) {
    const float* enc = (const float*)d_in[0];
    const float* cb  = (const float*)d_in[1];
    float* out = (float*)d_out;

    unsigned short* pk = (unsigned short*)((char*)d_ws + PK_OFF);
    float* cbn  = (float*)((char*)d_ws + CBN_OFF);
    float* psq  = (float*)((char*)d_ws + PSQ_OFF);
    float* psm  = (float*)((char*)d_ws + PSM_OFF);
    unsigned* done = (unsigned*)((char*)d_ws + DONE_OFF);

    prep_cb<<<64, 256, 0, stream>>>(cb, pk, cbn, done);
    vq_fused<<<512, 256, 0, stream>>>(enc, out, pk, cbn, psq, psm, done);
}